// Round 2
// baseline (9726.409 us; speedup 1.0000x reference)
//
#include <hip/hip_runtime.h>

#define HWX 65536   // 256*256
#define WID 256
#define HEI 256
#define EPSV 1e-5f

// d_out element offsets (fp32 elements), concatenated tuple order
#define O0 0u           // features        (4,128,256,256)
#define O1 33554432u    // region_logits   (4,3,256,256)
#define O2 34340864u    // anomaly_logits  (4,1,256,256)
#define O3 34603008u    // all_matches     (4,30,256,256)
#define O4 42467328u    // anomaly_matches (4,32,256,256)
#define O5 50855936u    // quality_scores  (4,1,256,256)
#define O6 51118080u    // region_probs    (4,3,256,256)
#define O7 51904512u    // anomaly_probs   (4,1,256,256)

// ---------------- conv1: 3 -> 64, 3x3 pad1, + BN stats ----------------
__global__ __launch_bounds__(256) void k_conv1(const float* __restrict__ x,
                                               const float* __restrict__ w,
                                               const float* __restrict__ bias,
                                               float* __restrict__ out,
                                               float* __restrict__ ssum,
                                               float* __restrict__ sqsum) {
    const int h = blockIdx.x, co = blockIdx.y, b = blockIdx.z;
    const int t = threadIdx.x;
    __shared__ float wl[27];
    __shared__ float red[8];
    if (t < 27) wl[t] = w[co * 27 + t];
    __syncthreads();
    float acc = bias[co];
    #pragma unroll
    for (int ci = 0; ci < 3; ci++) {
        #pragma unroll
        for (int kh = 0; kh < 3; kh++) {
            int hh = h + kh - 1;
            if ((unsigned)hh >= HEI) continue;
            const float* row = x + ((size_t)(b * 3 + ci) * HEI + hh) * WID;
            float w0 = wl[ci * 9 + kh * 3 + 0];
            float w1 = wl[ci * 9 + kh * 3 + 1];
            float w2 = wl[ci * 9 + kh * 3 + 2];
            float xc = row[t];
            float xm = (t > 0) ? row[t - 1] : 0.f;
            float xp = (t < WID - 1) ? row[t + 1] : 0.f;
            acc += xm * w0 + xc * w1 + xp * w2;
        }
    }
    out[((size_t)(b * 64 + co) * HEI + h) * WID + t] = acc;
    // block reduction for BN stats
    float s = acc, q = acc * acc;
    #pragma unroll
    for (int off = 32; off; off >>= 1) {
        s += __shfl_down(s, off, 64);
        q += __shfl_down(q, off, 64);
    }
    int lane = t & 63, wv = t >> 6;
    if (lane == 0) { red[wv] = s; red[4 + wv] = q; }
    __syncthreads();
    if (t == 0) atomicAdd(&ssum[co], red[0] + red[1] + red[2] + red[3]);
    else if (t == 1) atomicAdd(&sqsum[co], red[4] + red[5] + red[6] + red[7]);
}

// ---------------- finalize BN: scale/shift per channel ----------------
__global__ void k_finalize(const float* __restrict__ s, const float* __restrict__ q,
                           const float* __restrict__ g, const float* __restrict__ be,
                           float* __restrict__ sc, float* __restrict__ sh, int C) {
    int c = threadIdx.x;
    if (c >= C) return;
    const float invN = 1.f / 262144.f;
    float m = s[c] * invN;
    float v = fmaxf(q[c] * invN - m * m, 0.f);
    float scale = g[c] * rsqrtf(v + EPSV);
    sc[c] = scale;
    sh[c] = be[c] - m * scale;
}

// ---------------- elementwise BN + ReLU (float4 per thread, in-place safe) --
__global__ __launch_bounds__(256) void k_bnrelu(const float4* __restrict__ raw,
                                                const float* __restrict__ sc,
                                                const float* __restrict__ sh,
                                                float4* __restrict__ out, int C) {
    size_t i = (size_t)blockIdx.x * 256 + threadIdx.x;
    int c = (int)(i >> 14) % C;   // (4*i / 65536) % C
    float s = sc[c], h0 = sh[c];
    float4 r = raw[i];
    float4 o;
    o.x = fmaxf(r.x * s + h0, 0.f);
    o.y = fmaxf(r.y * s + h0, 0.f);
    o.z = fmaxf(r.z * s + h0, 0.f);
    o.w = fmaxf(r.w * s + h0, 0.f);
    out[i] = o;
}

// ---------------- conv2: 64 -> 128, 3x3 pad1, + BN stats ----------------
__global__ __launch_bounds__(256) void k_conv2(const float* __restrict__ in,
                                               const float* __restrict__ w,
                                               const float* __restrict__ bias,
                                               float* __restrict__ out,
                                               float* __restrict__ ssum,
                                               float* __restrict__ sqsum) {
    const int h = blockIdx.x, co = blockIdx.y, b = blockIdx.z;
    const int t = threadIdx.x;
    __shared__ float wl[576];
    __shared__ float red[8];
    for (int i = t; i < 576; i += 256) wl[i] = w[(size_t)co * 576 + i];
    __syncthreads();
    float acc = bias[co];
    for (int ci = 0; ci < 64; ci++) {
        const float* base = in + ((size_t)(b * 64 + ci) * HEI) * WID;
        const float* wc = wl + ci * 9;
        #pragma unroll
        for (int kh = 0; kh < 3; kh++) {
            int hh = h + kh - 1;
            if ((unsigned)hh >= HEI) continue;
            const float* row = base + (size_t)hh * WID;
            float xc = row[t];
            float xm = (t > 0) ? row[t - 1] : 0.f;
            float xp = (t < WID - 1) ? row[t + 1] : 0.f;
            acc += xm * wc[kh * 3 + 0] + xc * wc[kh * 3 + 1] + xp * wc[kh * 3 + 2];
        }
    }
    out[((size_t)(b * 128 + co) * HEI + h) * WID + t] = acc;
    float s = acc, q = acc * acc;
    #pragma unroll
    for (int off = 32; off; off >>= 1) {
        s += __shfl_down(s, off, 64);
        q += __shfl_down(q, off, 64);
    }
    int lane = t & 63, wv = t >> 6;
    if (lane == 0) { red[wv] = s; red[4 + wv] = q; }
    __syncthreads();
    if (t == 0) atomicAdd(&ssum[co], red[0] + red[1] + red[2] + red[3]);
    else if (t == 1) atomicAdd(&sqsum[co], red[4] + red[5] + red[6] + red[7]);
}

// ---------------- pattern-match convs: 128 -> 62, 3x3 pad1, sigmoid ----------------
__global__ __launch_bounds__(256) void k_match(const float* __restrict__ feat,
                                               const float* __restrict__ core,
                                               const float* __restrict__ clad,
                                               const float* __restrict__ ferr,
                                               const float* __restrict__ anom,
                                               float* __restrict__ out_all,
                                               float* __restrict__ out_anom) {
    const int h = blockIdx.x, cm = blockIdx.y, b = blockIdx.z;
    const int t = threadIdx.x;
    __shared__ float wl[1152];
    const float* wsrc;
    if (cm < 10)      wsrc = core + (size_t)cm * 1152;
    else if (cm < 20) wsrc = clad + (size_t)(cm - 10) * 1152;
    else if (cm < 30) wsrc = ferr + (size_t)(cm - 20) * 1152;
    else              wsrc = anom + (size_t)(cm - 30) * 1152;
    for (int i = t; i < 1152; i += 256) wl[i] = wsrc[i];
    __syncthreads();
    float acc = 0.f;
    for (int ci = 0; ci < 128; ci++) {
        const float* base = feat + ((size_t)(b * 128 + ci) * HEI) * WID;
        const float* wc = wl + ci * 9;
        #pragma unroll
        for (int kh = 0; kh < 3; kh++) {
            int hh = h + kh - 1;
            if ((unsigned)hh >= HEI) continue;
            const float* row = base + (size_t)hh * WID;
            float xc = row[t];
            float xm = (t > 0) ? row[t - 1] : 0.f;
            float xp = (t < WID - 1) ? row[t + 1] : 0.f;
            acc += xm * wc[kh * 3 + 0] + xc * wc[kh * 3 + 1] + xp * wc[kh * 3 + 2];
        }
    }
    float sig = 1.f / (1.f + __expf(-acc));
    if (cm < 30) out_all[((size_t)(b * 30 + cm) * HEI + h) * WID + t] = sig;
    else         out_anom[((size_t)(b * 32 + (cm - 30)) * HEI + h) * WID + t] = sig;
}

// ---------------- fused 1x1 heads: qa1+relu, qa2+sigmoid, cls+softmax ----------------
__global__ __launch_bounds__(256) void k_heads(const float* __restrict__ dout,
                                               const float* __restrict__ qa1w,
                                               const float* __restrict__ qa1b,
                                               const float* __restrict__ qa2w,
                                               const float* __restrict__ qa2b,
                                               const float* __restrict__ clsw,
                                               const float* __restrict__ clsb,
                                               float* __restrict__ out) {
    __shared__ __align__(16) float lw[190 * 68];
    __shared__ float lq2[64];
    __shared__ float lb[70];
    const int t = threadIdx.x;
    for (int i = t; i < 190 * 64; i += 256) { int j = i / 190, k = i - j * 190; lw[k * 68 + j] = qa1w[i]; }
    for (int i = t; i < 190 * 4;  i += 256) { int c = i / 190, k = i - c * 190; lw[k * 68 + 64 + c] = clsw[i]; }
    if (t < 64) { lq2[t] = qa2w[t]; lb[t] = qa1b[t]; }
    if (t < 4) lb[64 + t] = clsb[t];
    if (t == 0) lb[68] = qa2b[0];
    __syncthreads();
    const int px = blockIdx.x * 256 + t;
    const int b = blockIdx.y;
    const float* feat = dout + O0 + (size_t)b * 128 * HWX + px;
    const float* amat = dout + O3 + (size_t)b * 30 * HWX + px;
    const float* anm  = dout + O4 + (size_t)b * 32 * HWX + px;
    float acc[64];
    #pragma unroll
    for (int j = 0; j < 64; j++) acc[j] = lb[j];
    float c0 = lb[64], c1 = lb[65], c2 = lb[66], c3 = lb[67];
    for (int k = 0; k < 190; k++) {
        float val;
        if (k < 128)      val = feat[(size_t)k * HWX];
        else if (k < 158) val = amat[(size_t)(k - 128) * HWX];
        else              val = anm[(size_t)(k - 158) * HWX];
        const float4* wr = (const float4*)(lw + k * 68);
        #pragma unroll
        for (int j = 0; j < 16; j++) {
            float4 wv = wr[j];
            acc[4 * j + 0] += val * wv.x;
            acc[4 * j + 1] += val * wv.y;
            acc[4 * j + 2] += val * wv.z;
            acc[4 * j + 3] += val * wv.w;
        }
        float4 wc = wr[16];
        c0 += val * wc.x; c1 += val * wc.y; c2 += val * wc.z; c3 += val * wc.w;
    }
    float qa = lb[68];
    #pragma unroll
    for (int j = 0; j < 64; j++) qa += fmaxf(acc[j], 0.f) * lq2[j];
    float quality = 1.f / (1.f + __expf(-qa));
    float m = fmaxf(c0, fmaxf(c1, c2));
    float e0 = __expf(c0 - m), e1 = __expf(c1 - m), e2 = __expf(c2 - m);
    float inv = 1.f / (e0 + e1 + e2);
    size_t hw = (size_t)px;
    out[O1 + ((size_t)b * 3 + 0) * HWX + hw] = c0;
    out[O1 + ((size_t)b * 3 + 1) * HWX + hw] = c1;
    out[O1 + ((size_t)b * 3 + 2) * HWX + hw] = c2;
    out[O2 + (size_t)b * HWX + hw] = c3;
    out[O5 + (size_t)b * HWX + hw] = quality;
    out[O6 + ((size_t)b * 3 + 0) * HWX + hw] = e0 * inv;
    out[O6 + ((size_t)b * 3 + 1) * HWX + hw] = e1 * inv;
    out[O6 + ((size_t)b * 3 + 2) * HWX + hw] = e2 * inv;
    out[O7 + (size_t)b * HWX + hw] = 1.f / (1.f + __expf(-c3));
}

extern "C" void kernel_launch(void* const* d_in, const int* in_sizes, int n_in,
                              void* d_out, int out_size, void* d_ws, size_t ws_size,
                              hipStream_t stream) {
    (void)in_sizes; (void)n_in; (void)out_size; (void)ws_size;
    const float* x    = (const float*)d_in[0];
    const float* w1   = (const float*)d_in[1];
    const float* b1   = (const float*)d_in[2];
    const float* g1   = (const float*)d_in[3];
    const float* be1  = (const float*)d_in[4];
    const float* w2   = (const float*)d_in[5];
    const float* b2   = (const float*)d_in[6];
    const float* g2   = (const float*)d_in[7];
    const float* be2  = (const float*)d_in[8];
    const float* core = (const float*)d_in[9];
    const float* clad = (const float*)d_in[10];
    const float* ferr = (const float*)d_in[11];
    const float* anom = (const float*)d_in[12];
    const float* qa1w = (const float*)d_in[13];
    const float* qa1b = (const float*)d_in[14];
    const float* qa2w = (const float*)d_in[15];
    const float* qa2b = (const float*)d_in[16];
    const float* clsw = (const float*)d_in[17];
    const float* clsb = (const float*)d_in[18];

    char* ws = (char*)d_ws;
    float* stats = (float*)ws;        // [0..768) floats
    float* s1 = stats + 0;            // 64
    float* q1 = stats + 64;           // 64
    float* s2 = stats + 128;          // 128
    float* q2 = stats + 256;          // 128
    float* sc1 = stats + 384;         // 64
    float* sh1 = stats + 448;         // 64
    float* sc2 = stats + 512;         // 128
    float* sh2 = stats + 640;         // 128
    float* hbuf = (float*)(ws + 4096);   // conv1 raw -> bnrelu in-place (64 MB)
    float* dout = (float*)d_out;

    hipMemsetAsync(stats, 0, 384 * sizeof(float), stream);

    dim3 blk(256);
    k_conv1<<<dim3(256, 64, 4), blk, 0, stream>>>(x, w1, b1, hbuf, s1, q1);
    k_finalize<<<1, 128, 0, stream>>>(s1, q1, g1, be1, sc1, sh1, 64);
    k_bnrelu<<<16384, blk, 0, stream>>>((const float4*)hbuf, sc1, sh1, (float4*)hbuf, 64);
    // conv2 raw straight into d_out features region, then BN+ReLU in-place
    k_conv2<<<dim3(256, 128, 4), blk, 0, stream>>>(hbuf, w2, b2, dout + O0, s2, q2);
    k_finalize<<<1, 128, 0, stream>>>(s2, q2, g2, be2, sc2, sh2, 128);
    k_bnrelu<<<32768, blk, 0, stream>>>((const float4*)(dout + O0), sc2, sh2, (float4*)(dout + O0), 128);
    k_match<<<dim3(256, 62, 4), blk, 0, stream>>>(dout + O0, core, clad, ferr, anom, dout + O3, dout + O4);
    k_heads<<<dim3(256, 4), blk, 0, stream>>>(dout, qa1w, qa1b, qa2w, qa2b, clsw, clsb, dout);
}

// Round 3
// 2261.285 us; speedup vs baseline: 4.3013x; 4.3013x over previous
//
#include <hip/hip_runtime.h>

#define HWX 65536   // 256*256
#define WID 256
#define HEI 256
#define EPSV 1e-5f

// d_out element offsets (fp32 elements), concatenated tuple order
#define O0 0u           // features        (4,128,256,256)
#define O1 33554432u    // region_logits   (4,3,256,256)
#define O2 34340864u    // anomaly_logits  (4,1,256,256)
#define O3 34603008u    // all_matches     (4,30,256,256)
#define O4 42467328u    // anomaly_matches (4,32,256,256)
#define O5 50855936u    // quality_scores  (4,1,256,256)
#define O6 51118080u    // region_probs    (4,3,256,256)
#define O7 51904512u    // anomaly_probs   (4,1,256,256)

// ---------------- tiled direct conv: 32 Cout x 256 px per block -------------
// Thread: 4 co x 8 px register tile. LDS: input chunk (CICH ci x 3 rows,
// halo-padded) + transposed weights (pad-33 stride, conflict-free).
template<int CIN, int CICH, bool STATS, bool MATCH>
__global__ __launch_bounds__(256) void k_conv_t(
    const float* __restrict__ in, const float* __restrict__ w,
    const float* __restrict__ bias, float* __restrict__ out,
    float* __restrict__ out2, int Cout,
    float* __restrict__ ssum, float* __restrict__ sqsum)
{
    const int h = blockIdx.x, cb = blockIdx.y, b = blockIdx.z;
    const int t = threadIdx.x;
    const int pg = t & 31, cg = t >> 5;
    const int px0 = pg * 8, c0 = cg * 4;
    const int cbase = cb * 32;

    __shared__ float xs[CICH][3][258];
    __shared__ float wl[CICH * 9 * 33];

    float acc[4][8];
    #pragma unroll
    for (int c = 0; c < 4; c++) {
        float bv = MATCH ? 0.f : bias[cbase + c0 + c];
        #pragma unroll
        for (int p = 0; p < 8; p++) acc[c][p] = bv;
    }

    const int NCHUNK = CIN / CICH;
    for (int ch = 0; ch < NCHUNK; ch++) {
        // stage input chunk (coalesced scalar loads, conflict-free LDS writes)
        for (int idx = t; idx < CICH * 768; idx += 256) {
            int ci = idx / 768, rem = idx - ci * 768;
            int r = rem >> 8, px = rem & 255;
            int hh = h + r - 1;
            float v = 0.f;
            if ((unsigned)hh < HEI)
                v = in[((size_t)(b * CIN + ch * CICH + ci) * HEI + hh) * WID + px];
            xs[ci][r][1 + px] = v;
        }
        if (t < CICH * 6) {           // halo zeros
            int ci = t / 6, rr = t - ci * 6;
            xs[ci][rr >> 1][(rr & 1) ? 257 : 0] = 0.f;
        }
        // stage weights: wl[(ci*9+k)*33 + co], coalesced global reads
        for (int idx = t; idx < CICH * 9 * 32; idx += 256) {
            int co = idx / (CICH * 9);
            int rem = idx - co * (CICH * 9);
            int cm = cbase + co;
            float v = 0.f;
            if (!MATCH || cm < 62)
                v = w[(size_t)cm * (CIN * 9) + ch * (CICH * 9) + rem];
            wl[rem * 33 + co] = v;
        }
        __syncthreads();
        for (int ci = 0; ci < CICH; ci++) {
            #pragma unroll
            for (int kh = 0; kh < 3; kh++) {
                float xv[10];
                #pragma unroll
                for (int j = 0; j < 10; j++) xv[j] = xs[ci][kh][px0 + j];
                float wv[3][4];
                #pragma unroll
                for (int kw = 0; kw < 3; kw++)
                    #pragma unroll
                    for (int c = 0; c < 4; c++)
                        wv[kw][c] = wl[(ci * 9 + kh * 3 + kw) * 33 + c0 + c];
                #pragma unroll
                for (int c = 0; c < 4; c++)
                    #pragma unroll
                    for (int p = 0; p < 8; p++)
                        acc[c][p] += xv[p] * wv[0][c] + xv[p + 1] * wv[1][c]
                                   + xv[p + 2] * wv[2][c];
            }
        }
        __syncthreads();
    }

    if (!MATCH) {
        #pragma unroll
        for (int c = 0; c < 4; c++) {
            int cm = cbase + c0 + c;
            float* op = out + (((size_t)(b * Cout + cm) * HEI + h) * WID + px0);
            float4 v0 = make_float4(acc[c][0], acc[c][1], acc[c][2], acc[c][3]);
            float4 v1 = make_float4(acc[c][4], acc[c][5], acc[c][6], acc[c][7]);
            ((float4*)op)[0] = v0;
            ((float4*)op)[1] = v1;
        }
    } else {
        #pragma unroll
        for (int c = 0; c < 4; c++) {
            int cm = cbase + c0 + c;
            if (cm < 62) {
                float* op;
                if (cm < 30) op = out  + (((size_t)(b * 30 + cm) * HEI + h) * WID + px0);
                else         op = out2 + (((size_t)(b * 32 + (cm - 30)) * HEI + h) * WID + px0);
                float4 v0, v1;
                v0.x = 1.f / (1.f + __expf(-acc[c][0]));
                v0.y = 1.f / (1.f + __expf(-acc[c][1]));
                v0.z = 1.f / (1.f + __expf(-acc[c][2]));
                v0.w = 1.f / (1.f + __expf(-acc[c][3]));
                v1.x = 1.f / (1.f + __expf(-acc[c][4]));
                v1.y = 1.f / (1.f + __expf(-acc[c][5]));
                v1.z = 1.f / (1.f + __expf(-acc[c][6]));
                v1.w = 1.f / (1.f + __expf(-acc[c][7]));
                ((float4*)op)[0] = v0;
                ((float4*)op)[1] = v1;
            }
        }
    }

    if (STATS) {
        __syncthreads();
        float* red = &xs[0][0][0];   // reuse: needs 2*32*33=2112 floats (xs >= 2322)
        #pragma unroll
        for (int c = 0; c < 4; c++) {
            float sv = 0.f, qv = 0.f;
            #pragma unroll
            for (int p = 0; p < 8; p++) { sv += acc[c][p]; qv += acc[c][p] * acc[c][p]; }
            red[(c0 + c) * 33 + pg] = sv;
            red[1056 + (c0 + c) * 33 + pg] = qv;
        }
        __syncthreads();
        if (t < 64) {
            int co = t & 31, v = t >> 5;
            const float* base = red + v * 1056 + co * 33;
            float sum = 0.f;
            #pragma unroll
            for (int i = 0; i < 32; i++) sum += base[i];
            atomicAdd((v ? sqsum : ssum) + cbase + co, sum);
        }
    }
}

// ---------------- finalize BN: scale/shift per channel ----------------
__global__ void k_finalize(const float* __restrict__ s, const float* __restrict__ q,
                           const float* __restrict__ g, const float* __restrict__ be,
                           float* __restrict__ sc, float* __restrict__ sh, int C) {
    int c = threadIdx.x;
    if (c >= C) return;
    const float invN = 1.f / 262144.f;
    float m = s[c] * invN;
    float v = fmaxf(q[c] * invN - m * m, 0.f);
    float scale = g[c] * rsqrtf(v + EPSV);
    sc[c] = scale;
    sh[c] = be[c] - m * scale;
}

// ---------------- elementwise BN + ReLU (float4 per thread) ----------------
__global__ __launch_bounds__(256) void k_bnrelu(const float4* __restrict__ raw,
                                                const float* __restrict__ sc,
                                                const float* __restrict__ sh,
                                                float4* __restrict__ out, int C) {
    size_t i = (size_t)blockIdx.x * 256 + threadIdx.x;
    int c = (int)(i >> 14) % C;
    float s = sc[c], h0 = sh[c];
    float4 r = raw[i];
    float4 o;
    o.x = fmaxf(r.x * s + h0, 0.f);
    o.y = fmaxf(r.y * s + h0, 0.f);
    o.z = fmaxf(r.z * s + h0, 0.f);
    o.w = fmaxf(r.w * s + h0, 0.f);
    out[i] = o;
}

// ---------------- fused 1x1 heads: qa1+relu, qa2+sigmoid, cls+softmax -------
__global__ __launch_bounds__(256) void k_heads(const float* __restrict__ dout,
                                               const float* __restrict__ qa1w,
                                               const float* __restrict__ qa1b,
                                               const float* __restrict__ qa2w,
                                               const float* __restrict__ qa2b,
                                               const float* __restrict__ clsw,
                                               const float* __restrict__ clsb,
                                               float* __restrict__ out) {
    __shared__ __align__(16) float lw[190 * 68];
    __shared__ float lq2[64];
    __shared__ float lb[70];
    const int t = threadIdx.x;
    for (int i = t; i < 190 * 64; i += 256) { int j = i / 190, k = i - j * 190; lw[k * 68 + j] = qa1w[i]; }
    for (int i = t; i < 190 * 4;  i += 256) { int c = i / 190, k = i - c * 190; lw[k * 68 + 64 + c] = clsw[i]; }
    if (t < 64) { lq2[t] = qa2w[t]; lb[t] = qa1b[t]; }
    if (t < 4) lb[64 + t] = clsb[t];
    if (t == 0) lb[68] = qa2b[0];
    __syncthreads();
    const int px = blockIdx.x * 256 + t;
    const int b = blockIdx.y;
    const float* feat = dout + O0 + (size_t)b * 128 * HWX + px;
    const float* amat = dout + O3 + (size_t)b * 30 * HWX + px;
    const float* anm  = dout + O4 + (size_t)b * 32 * HWX + px;
    float acc[64];
    #pragma unroll
    for (int j = 0; j < 64; j++) acc[j] = lb[j];
    float c0 = lb[64], c1 = lb[65], c2 = lb[66], c3 = lb[67];
    for (int k = 0; k < 190; k++) {
        float val;
        if (k < 128)      val = feat[(size_t)k * HWX];
        else if (k < 158) val = amat[(size_t)(k - 128) * HWX];
        else              val = anm[(size_t)(k - 158) * HWX];
        const float4* wr = (const float4*)(lw + k * 68);
        #pragma unroll
        for (int j = 0; j < 16; j++) {
            float4 wv = wr[j];
            acc[4 * j + 0] += val * wv.x;
            acc[4 * j + 1] += val * wv.y;
            acc[4 * j + 2] += val * wv.z;
            acc[4 * j + 3] += val * wv.w;
        }
        float4 wc = wr[16];
        c0 += val * wc.x; c1 += val * wc.y; c2 += val * wc.z; c3 += val * wc.w;
    }
    float qa = lb[68];
    #pragma unroll
    for (int j = 0; j < 64; j++) qa += fmaxf(acc[j], 0.f) * lq2[j];
    float quality = 1.f / (1.f + __expf(-qa));
    float m = fmaxf(c0, fmaxf(c1, c2));
    float e0 = __expf(c0 - m), e1 = __expf(c1 - m), e2 = __expf(c2 - m);
    float inv = 1.f / (e0 + e1 + e2);
    size_t hw = (size_t)px;
    out[O1 + ((size_t)b * 3 + 0) * HWX + hw] = c0;
    out[O1 + ((size_t)b * 3 + 1) * HWX + hw] = c1;
    out[O1 + ((size_t)b * 3 + 2) * HWX + hw] = c2;
    out[O2 + (size_t)b * HWX + hw] = c3;
    out[O5 + (size_t)b * HWX + hw] = quality;
    out[O6 + ((size_t)b * 3 + 0) * HWX + hw] = e0 * inv;
    out[O6 + ((size_t)b * 3 + 1) * HWX + hw] = e1 * inv;
    out[O6 + ((size_t)b * 3 + 2) * HWX + hw] = e2 * inv;
    out[O7 + (size_t)b * HWX + hw] = 1.f / (1.f + __expf(-c3));
}

extern "C" void kernel_launch(void* const* d_in, const int* in_sizes, int n_in,
                              void* d_out, int out_size, void* d_ws, size_t ws_size,
                              hipStream_t stream) {
    (void)in_sizes; (void)n_in; (void)out_size; (void)ws_size;
    const float* x    = (const float*)d_in[0];
    const float* w1   = (const float*)d_in[1];
    const float* b1   = (const float*)d_in[2];
    const float* g1   = (const float*)d_in[3];
    const float* be1  = (const float*)d_in[4];
    const float* w2   = (const float*)d_in[5];
    const float* b2   = (const float*)d_in[6];
    const float* g2   = (const float*)d_in[7];
    const float* be2  = (const float*)d_in[8];
    const float* core = (const float*)d_in[9];
    const float* clad = (const float*)d_in[10];
    const float* ferr = (const float*)d_in[11];
    const float* anom = (const float*)d_in[12];
    const float* qa1w = (const float*)d_in[13];
    const float* qa1b = (const float*)d_in[14];
    const float* qa2w = (const float*)d_in[15];
    const float* qa2b = (const float*)d_in[16];
    const float* clsw = (const float*)d_in[17];
    const float* clsb = (const float*)d_in[18];

    char* ws = (char*)d_ws;
    float* stats = (float*)ws;
    float* s1 = stats + 0;            // 64
    float* q1 = stats + 64;           // 64
    float* s2 = stats + 128;          // 128
    float* q2 = stats + 256;          // 128
    float* sc1 = stats + 384;         // 64
    float* sh1 = stats + 448;         // 64
    float* sc2 = stats + 512;         // 128
    float* sh2 = stats + 640;         // 128
    float* hbuf = (float*)(ws + 4096);                       // 64 MB
    float* wcat = (float*)(ws + 4096 + 67108864ull);         // 62*1152*4 = 285 KB
    float* dout = (float*)d_out;

    hipMemsetAsync(stats, 0, 384 * sizeof(float), stream);
    // concatenate match weights: [core(10) | clad(10) | ferr(10) | anom(32)] x 1152
    hipMemcpyAsync(wcat,             core, 10 * 1152 * 4, hipMemcpyDeviceToDevice, stream);
    hipMemcpyAsync(wcat + 10 * 1152, clad, 10 * 1152 * 4, hipMemcpyDeviceToDevice, stream);
    hipMemcpyAsync(wcat + 20 * 1152, ferr, 10 * 1152 * 4, hipMemcpyDeviceToDevice, stream);
    hipMemcpyAsync(wcat + 30 * 1152, anom, 32 * 1152 * 4, hipMemcpyDeviceToDevice, stream);

    dim3 blk(256);
    // conv1: 3->64
    k_conv_t<3, 3, true, false><<<dim3(256, 2, 4), blk, 0, stream>>>(
        x, w1, b1, hbuf, nullptr, 64, s1, q1);
    k_finalize<<<1, 128, 0, stream>>>(s1, q1, g1, be1, sc1, sh1, 64);
    k_bnrelu<<<16384, blk, 0, stream>>>((const float4*)hbuf, sc1, sh1, (float4*)hbuf, 64);
    // conv2: 64->128, raw into d_out features region, BN+ReLU in-place
    k_conv_t<64, 8, true, false><<<dim3(256, 4, 4), blk, 0, stream>>>(
        hbuf, w2, b2, dout + O0, nullptr, 128, s2, q2);
    k_finalize<<<1, 128, 0, stream>>>(s2, q2, g2, be2, sc2, sh2, 128);
    k_bnrelu<<<32768, blk, 0, stream>>>((const float4*)(dout + O0), sc2, sh2, (float4*)(dout + O0), 128);
    // match: 128->62 (+sigmoid), split outputs
    k_conv_t<128, 8, false, true><<<dim3(256, 2, 4), blk, 0, stream>>>(
        dout + O0, wcat, nullptr, dout + O3, dout + O4, 62, nullptr, nullptr);
    k_heads<<<dim3(256, 4), blk, 0, stream>>>(dout, qa1w, qa1b, qa2w, qa2b, clsw, clsb, dout);
}

// Round 4
// 1639.433 us; speedup vs baseline: 5.9328x; 1.3793x over previous
//
#include <hip/hip_runtime.h>
#include <hip/hip_bf16.h>

typedef unsigned short u16;
typedef __attribute__((ext_vector_type(8)))  short s8v;
typedef __attribute__((ext_vector_type(4)))  short s4v;
typedef __attribute__((ext_vector_type(16))) float f16v;

#define HWX 65536
#define EPSV 1e-5f

// d_out element offsets (fp32), concatenated tuple order
#define O0 0u
#define O1 33554432u
#define O2 34340864u
#define O3 34603008u
#define O4 42467328u
#define O5 50855936u
#define O6 51118080u
#define O7 51904512u

__device__ __forceinline__ float u2f(u16 u) {
    union { unsigned int i; float f; } v; v.i = ((unsigned int)u) << 16; return v.f;
}
__device__ __forceinline__ u16 f2u(float f) {
    __hip_bfloat16 h = __float2bfloat16(f);
    return *reinterpret_cast<u16*>(&h);
}
__device__ __forceinline__ s8v ld8(const u16* p) {
    union { s8v v; s4v h[2]; } r;
    r.h[0] = *(const s4v*)p;
    r.h[1] = *(const s4v*)(p + 4);
    return r.v;
}

#define PHYS(i) ((i) + ((i) >> 5))

// ---------------- conv1: 3->64 fp32 direct (swizzled LDS), bf16 out + stats --
__global__ __launch_bounds__(256) void k_conv1(const float* __restrict__ x,
                                               const float* __restrict__ w,
                                               const float* __restrict__ bias,
                                               u16* __restrict__ out,
                                               float* __restrict__ ssum,
                                               float* __restrict__ sqsum) {
    const int h = blockIdx.x, cb = blockIdx.y, b = blockIdx.z;
    const int t = threadIdx.x;
    const int pg = t & 31, cg = t >> 5;
    const int px0 = pg * 8, c0 = cg * 4;
    const int cbase = cb * 32;

    __shared__ float xs[3][3][266];
    __shared__ float wl[27 * 33];
    __shared__ float red2[8];

    float acc[4][8];
    #pragma unroll
    for (int c = 0; c < 4; c++) {
        float bv = bias[cbase + c0 + c];
        #pragma unroll
        for (int p = 0; p < 8; p++) acc[c][p] = bv;
    }

    for (int idx = t; idx < 3 * 768; idx += 256) {
        int ci = idx / 768, rem = idx - ci * 768;
        int r = rem >> 8, px = rem & 255;
        int hh = h + r - 1;
        float v = 0.f;
        if ((unsigned)hh < 256u)
            v = x[((size_t)(b * 3 + ci) * 256 + hh) * 256 + px];
        xs[ci][r][PHYS(1 + px)] = v;
    }
    if (t < 18) {
        int ci = t / 6, rr = t - ci * 6;
        xs[ci][rr >> 1][(rr & 1) ? PHYS(257) : 0] = 0.f;
    }
    for (int idx = t; idx < 27 * 32; idx += 256) {
        int co = idx / 27, rem = idx - co * 27;
        wl[rem * 33 + co] = w[(cbase + co) * 27 + rem];
    }
    __syncthreads();

    for (int ci = 0; ci < 3; ci++) {
        #pragma unroll
        for (int kh = 0; kh < 3; kh++) {
            float xv[10];
            #pragma unroll
            for (int j = 0; j < 10; j++) xv[j] = xs[ci][kh][PHYS(px0 + j)];
            float wv[3][4];
            #pragma unroll
            for (int kw = 0; kw < 3; kw++)
                #pragma unroll
                for (int c = 0; c < 4; c++)
                    wv[kw][c] = wl[(ci * 9 + kh * 3 + kw) * 33 + c0 + c];
            #pragma unroll
            for (int c = 0; c < 4; c++)
                #pragma unroll
                for (int p = 0; p < 8; p++)
                    acc[c][p] += xv[p] * wv[0][c] + xv[p + 1] * wv[1][c]
                               + xv[p + 2] * wv[2][c];
        }
    }

    #pragma unroll
    for (int c = 0; c < 4; c++) {
        int cm = cbase + c0 + c;
        u16* op = out + (((size_t)(b * 64 + cm) * 256 + h) * 256 + px0);
        #pragma unroll
        for (int p = 0; p < 8; p++) op[p] = f2u(acc[c][p]);
    }

    __syncthreads();
    float* red = &xs[0][0][0];
    #pragma unroll
    for (int c = 0; c < 4; c++) {
        float sv = 0.f, qv = 0.f;
        #pragma unroll
        for (int p = 0; p < 8; p++) { sv += acc[c][p]; qv += acc[c][p] * acc[c][p]; }
        red[(c0 + c) * 33 + pg] = sv;
        red[1056 + (c0 + c) * 33 + pg] = qv;
    }
    __syncthreads();
    if (t < 64) {
        int co = t & 31, v = t >> 5;
        const float* base = red + v * 1056 + co * 33;
        float sum = 0.f;
        #pragma unroll
        for (int i = 0; i < 32; i++) sum += base[i];
        atomicAdd((v ? sqsum : ssum) + cbase + co, sum);
    }
    (void)red2;
}

// ---------------- finalize BN ----------------
__global__ void k_finalize(const float* __restrict__ s, const float* __restrict__ q,
                           const float* __restrict__ g, const float* __restrict__ be,
                           float* __restrict__ sc, float* __restrict__ sh, int C) {
    int c = threadIdx.x;
    if (c >= C) return;
    const float invN = 1.f / 262144.f;
    float m = s[c] * invN;
    float v = fmaxf(q[c] * invN - m * m, 0.f);
    float scale = g[c] * rsqrtf(v + EPSV);
    sc[c] = scale;
    sh[c] = be[c] - m * scale;
}

// ---------------- BN+ReLU on bf16 buffer (in place) ----------------
__global__ __launch_bounds__(256) void k_bnrelu_h(ushort4* __restrict__ buf,
                                                  const float* __restrict__ sc,
                                                  const float* __restrict__ sh) {
    size_t i = (size_t)blockIdx.x * 256 + threadIdx.x;
    int c = (int)(i >> 14) & 63;
    float s = sc[c], h0 = sh[c];
    ushort4 r = buf[i];
    ushort4 o;
    o.x = f2u(fmaxf(u2f(r.x) * s + h0, 0.f));
    o.y = f2u(fmaxf(u2f(r.y) * s + h0, 0.f));
    o.z = f2u(fmaxf(u2f(r.z) * s + h0, 0.f));
    o.w = f2u(fmaxf(u2f(r.w) * s + h0, 0.f));
    buf[i] = o;
}

// ---------------- BN+ReLU fp32 (features, in place) ----------------
__global__ __launch_bounds__(256) void k_bnrelu(float4* __restrict__ buf,
                                                const float* __restrict__ sc,
                                                const float* __restrict__ sh, int C) {
    size_t i = (size_t)blockIdx.x * 256 + threadIdx.x;
    int c = (int)(i >> 14) % C;
    float s = sc[c], h0 = sh[c];
    float4 r = buf[i];
    float4 o;
    o.x = fmaxf(r.x * s + h0, 0.f);
    o.y = fmaxf(r.y * s + h0, 0.f);
    o.z = fmaxf(r.z * s + h0, 0.f);
    o.w = fmaxf(r.w * s + h0, 0.f);
    buf[i] = o;
}

// ---------------- per-channel stats over raw conv2 out ----------------
__global__ __launch_bounds__(256) void k_stats(const float* __restrict__ raw,
                                               float* __restrict__ ssum,
                                               float* __restrict__ sqsum) {
    const int co = blockIdx.x, seg = blockIdx.y;
    const int t = threadIdx.x;
    __shared__ float red[8];
    float s = 0.f, q = 0.f;
    for (int b = 0; b < 4; b++) {
        const float4* p = (const float4*)(raw + ((size_t)(b * 128 + co) * HWX) + seg * 8192);
        for (int i = t; i < 2048; i += 256) {
            float4 v = p[i];
            s += v.x + v.y + v.z + v.w;
            q += v.x * v.x + v.y * v.y + v.z * v.z + v.w * v.w;
        }
    }
    #pragma unroll
    for (int off = 32; off; off >>= 1) {
        s += __shfl_down(s, off, 64);
        q += __shfl_down(q, off, 64);
    }
    int lane = t & 63, wv = t >> 6;
    if (lane == 0) { red[wv] = s; red[4 + wv] = q; }
    __syncthreads();
    if (t == 0) atomicAdd(&ssum[co], red[0] + red[1] + red[2] + red[3]);
    else if (t == 1) atomicAdd(&sqsum[co], red[4] + red[5] + red[6] + red[7]);
}

// ---------------- weight converters ----------------
__global__ void k_cvt(const float* __restrict__ in, u16* __restrict__ out, int n) {
    int i = blockIdx.x * 256 + threadIdx.x;
    if (i < n) out[i] = f2u(in[i]);
}
__global__ void k_cvt_split(const float* __restrict__ in, u16* __restrict__ hi,
                            u16* __restrict__ lo, int n) {
    int i = blockIdx.x * 256 + threadIdx.x;
    if (i < n) {
        float v = in[i];
        u16 hb = f2u(v);
        hi[i] = hb;
        lo[i] = f2u(v - u2f(hb));
    }
}

// ---------------- conv2 MFMA: 64->128, bf16 in, fp32 raw out ----------------
// Block: one (h,b) row, 128 co x 256 px. K-dim = kh*16+ci (48/chunk), kw outer.
__global__ __launch_bounds__(256, 2) void k_conv2_mf(
    const u16* __restrict__ hb, const u16* __restrict__ wb,
    const float* __restrict__ bias, float* __restrict__ out)
{
    const int h = blockIdx.x, b = blockIdx.y;
    const int t = threadIdx.x, l = t & 63, wv = t >> 6;
    const int kg = (l >> 5) * 8, nn = l & 31;

    __shared__ u16 xs[258 * 52];
    __shared__ u16 wl[3 * 128 * 52];

    f16v acc[2][4];
    #pragma unroll
    for (int pt = 0; pt < 2; pt++)
        #pragma unroll
        for (int s = 0; s < 4; s++)
            #pragma unroll
            for (int r = 0; r < 16; r++) acc[pt][s][r] = 0.f;

    for (int ci0 = 0; ci0 < 64; ci0 += 16) {
        for (int idx = t; idx < 12384; idx += 256) {
            int ci = idx / 774, rem = idx - ci * 774;
            int r = rem / 258, p = rem - r * 258;
            int hh = h + r - 1, px = p - 1;
            u16 v = 0;
            if ((unsigned)hh < 256u && (unsigned)px < 256u)
                v = hb[(((size_t)b * 64 + ci0 + ci) * 256 + hh) * 256 + px];
            xs[p * 52 + r * 16 + ci] = v;
        }
        for (int idx = t; idx < 18432; idx += 256) {
            int kw = idx / 6144, rem = idx - kw * 6144;
            int co = rem / 48, k = rem - co * 48;
            int kh = k >> 4, ci = ci0 + (k & 15);
            wl[(kw * 128 + co) * 52 + k] = wb[((size_t)co * 64 + ci) * 9 + kh * 3 + kw];
        }
        __syncthreads();
        #pragma unroll
        for (int kw = 0; kw < 3; kw++) {
            #pragma unroll
            for (int ks = 0; ks < 3; ks++) {
                int k0 = ks * 16 + kg;
                s8v af[4], bf[2];
                #pragma unroll
                for (int s = 0; s < 4; s++)
                    af[s] = ld8(&wl[(kw * 128 + s * 32 + nn) * 52 + k0]);
                #pragma unroll
                for (int pt = 0; pt < 2; pt++) {
                    int p = (wv * 2 + pt) * 32 + nn + kw;
                    bf[pt] = ld8(&xs[p * 52 + k0]);
                }
                #pragma unroll
                for (int pt = 0; pt < 2; pt++)
                    #pragma unroll
                    for (int s = 0; s < 4; s++)
                        acc[pt][s] = __builtin_amdgcn_mfma_f32_32x32x16_bf16(
                            af[s], bf[pt], acc[pt][s], 0, 0, 0);
            }
        }
        __syncthreads();
    }

    #pragma unroll
    for (int pt = 0; pt < 2; pt++) {
        int px = (wv * 2 + pt) * 32 + nn;
        #pragma unroll
        for (int s = 0; s < 4; s++) {
            #pragma unroll
            for (int r = 0; r < 16; r++) {
                int co = s * 32 + (r & 3) + 8 * (r >> 2) + 4 * (l >> 5);
                out[(((size_t)b * 128 + co) * 256 + h) * 256 + px] = acc[pt][s][r] + bias[co];
            }
        }
    }
}

// ---------------- match MFMA: 128->62, 3-term bf16 split, sigmoid ----------
__global__ __launch_bounds__(256, 1) void k_match_mf(
    const float* __restrict__ feat, const u16* __restrict__ whi,
    const u16* __restrict__ wlo, float* __restrict__ out_all,
    float* __restrict__ out_anom)
{
    const int h = blockIdx.x, b = blockIdx.y;
    const int t = threadIdx.x, l = t & 63, wv = t >> 6;
    const int kg = (l >> 5) * 8, nn = l & 31;

    __shared__ u16 xs[2 * 13416];     // [hi/lo][258][52]
    __shared__ u16 wlh[3 * 64 * 52];
    __shared__ u16 wll[3 * 64 * 52];

    f16v acc[2][2];
    #pragma unroll
    for (int pt = 0; pt < 2; pt++)
        #pragma unroll
        for (int s = 0; s < 2; s++)
            #pragma unroll
            for (int r = 0; r < 16; r++) acc[pt][s][r] = 0.f;

    for (int ci0 = 0; ci0 < 128; ci0 += 16) {
        for (int idx = t; idx < 12384; idx += 256) {
            int ci = idx / 774, rem = idx - ci * 774;
            int r = rem / 258, p = rem - r * 258;
            int hh = h + r - 1, px = p - 1;
            float v = 0.f;
            if ((unsigned)hh < 256u && (unsigned)px < 256u)
                v = feat[(((size_t)b * 128 + ci0 + ci) * 256 + hh) * 256 + px];
            u16 hb_ = f2u(v);
            xs[p * 52 + r * 16 + ci] = hb_;
            xs[13416 + p * 52 + r * 16 + ci] = f2u(v - u2f(hb_));
        }
        for (int idx = t; idx < 9216; idx += 256) {
            int kw = idx / 3072, rem = idx - kw * 3072;
            int co = rem / 48, k = rem - co * 48;
            int kh = k >> 4, ci = ci0 + (k & 15);
            u16 vh = 0, vl = 0;
            if (co < 62) {
                size_t off = (size_t)co * 1152 + ci * 9 + kh * 3 + kw;
                vh = whi[off]; vl = wlo[off];
            }
            wlh[(kw * 64 + co) * 52 + k] = vh;
            wll[(kw * 64 + co) * 52 + k] = vl;
        }
        __syncthreads();
        #pragma unroll
        for (int kw = 0; kw < 3; kw++) {
            #pragma unroll
            for (int ks = 0; ks < 3; ks++) {
                int k0 = ks * 16 + kg;
                s8v ah[2], al[2], xh[2], xl[2];
                #pragma unroll
                for (int s = 0; s < 2; s++) {
                    ah[s] = ld8(&wlh[(kw * 64 + s * 32 + nn) * 52 + k0]);
                    al[s] = ld8(&wll[(kw * 64 + s * 32 + nn) * 52 + k0]);
                }
                #pragma unroll
                for (int pt = 0; pt < 2; pt++) {
                    int p = (wv * 2 + pt) * 32 + nn + kw;
                    xh[pt] = ld8(&xs[p * 52 + k0]);
                    xl[pt] = ld8(&xs[13416 + p * 52 + k0]);
                }
                #pragma unroll
                for (int pt = 0; pt < 2; pt++)
                    #pragma unroll
                    for (int s = 0; s < 2; s++) {
                        acc[pt][s] = __builtin_amdgcn_mfma_f32_32x32x16_bf16(
                            ah[s], xh[pt], acc[pt][s], 0, 0, 0);
                        acc[pt][s] = __builtin_amdgcn_mfma_f32_32x32x16_bf16(
                            ah[s], xl[pt], acc[pt][s], 0, 0, 0);
                        acc[pt][s] = __builtin_amdgcn_mfma_f32_32x32x16_bf16(
                            al[s], xh[pt], acc[pt][s], 0, 0, 0);
                    }
            }
        }
        __syncthreads();
    }

    #pragma unroll
    for (int pt = 0; pt < 2; pt++) {
        int px = (wv * 2 + pt) * 32 + nn;
        #pragma unroll
        for (int s = 0; s < 2; s++) {
            #pragma unroll
            for (int r = 0; r < 16; r++) {
                int cm = s * 32 + (r & 3) + 8 * (r >> 2) + 4 * (l >> 5);
                float sg = 1.f / (1.f + __expf(-acc[pt][s][r]));
                if (cm < 30)
                    out_all[(((size_t)b * 30 + cm) * 256 + h) * 256 + px] = sg;
                else if (cm < 62)
                    out_anom[(((size_t)b * 32 + cm - 30) * 256 + h) * 256 + px] = sg;
            }
        }
    }
}

// ---------------- fused 1x1 heads ----------------
__global__ __launch_bounds__(256) void k_heads(const float* __restrict__ dout,
                                               const float* __restrict__ qa1w,
                                               const float* __restrict__ qa1b,
                                               const float* __restrict__ qa2w,
                                               const float* __restrict__ qa2b,
                                               const float* __restrict__ clsw,
                                               const float* __restrict__ clsb,
                                               float* __restrict__ out) {
    __shared__ __align__(16) float lw[190 * 68];
    __shared__ float lq2[64];
    __shared__ float lb[70];
    const int t = threadIdx.x;
    for (int i = t; i < 190 * 64; i += 256) { int j = i / 190, k = i - j * 190; lw[k * 68 + j] = qa1w[i]; }
    for (int i = t; i < 190 * 4;  i += 256) { int c = i / 190, k = i - c * 190; lw[k * 68 + 64 + c] = clsw[i]; }
    if (t < 64) { lq2[t] = qa2w[t]; lb[t] = qa1b[t]; }
    if (t < 4) lb[64 + t] = clsb[t];
    if (t == 0) lb[68] = qa2b[0];
    __syncthreads();
    const int px = blockIdx.x * 256 + t;
    const int b = blockIdx.y;
    const float* feat = dout + O0 + (size_t)b * 128 * HWX + px;
    const float* amat = dout + O3 + (size_t)b * 30 * HWX + px;
    const float* anm  = dout + O4 + (size_t)b * 32 * HWX + px;
    float acc[64];
    #pragma unroll
    for (int j = 0; j < 64; j++) acc[j] = lb[j];
    float c0 = lb[64], c1 = lb[65], c2 = lb[66], c3 = lb[67];
    for (int k = 0; k < 190; k++) {
        float val;
        if (k < 128)      val = feat[(size_t)k * HWX];
        else if (k < 158) val = amat[(size_t)(k - 128) * HWX];
        else              val = anm[(size_t)(k - 158) * HWX];
        const float4* wr = (const float4*)(lw + k * 68);
        #pragma unroll
        for (int j = 0; j < 16; j++) {
            float4 wvv = wr[j];
            acc[4 * j + 0] += val * wvv.x;
            acc[4 * j + 1] += val * wvv.y;
            acc[4 * j + 2] += val * wvv.z;
            acc[4 * j + 3] += val * wvv.w;
        }
        float4 wc = wr[16];
        c0 += val * wc.x; c1 += val * wc.y; c2 += val * wc.z; c3 += val * wc.w;
    }
    float qa = lb[68];
    #pragma unroll
    for (int j = 0; j < 64; j++) qa += fmaxf(acc[j], 0.f) * lq2[j];
    float quality = 1.f / (1.f + __expf(-qa));
    float m = fmaxf(c0, fmaxf(c1, c2));
    float e0 = __expf(c0 - m), e1 = __expf(c1 - m), e2 = __expf(c2 - m);
    float inv = 1.f / (e0 + e1 + e2);
    size_t hw = (size_t)px;
    out[O1 + ((size_t)b * 3 + 0) * HWX + hw] = c0;
    out[O1 + ((size_t)b * 3 + 1) * HWX + hw] = c1;
    out[O1 + ((size_t)b * 3 + 2) * HWX + hw] = c2;
    out[O2 + (size_t)b * HWX + hw] = c3;
    out[O5 + (size_t)b * HWX + hw] = quality;
    out[O6 + ((size_t)b * 3 + 0) * HWX + hw] = e0 * inv;
    out[O6 + ((size_t)b * 3 + 1) * HWX + hw] = e1 * inv;
    out[O6 + ((size_t)b * 3 + 2) * HWX + hw] = e2 * inv;
    out[O7 + (size_t)b * HWX + hw] = 1.f / (1.f + __expf(-c3));
}

extern "C" void kernel_launch(void* const* d_in, const int* in_sizes, int n_in,
                              void* d_out, int out_size, void* d_ws, size_t ws_size,
                              hipStream_t stream) {
    (void)in_sizes; (void)n_in; (void)out_size; (void)ws_size;
    const float* x    = (const float*)d_in[0];
    const float* w1   = (const float*)d_in[1];
    const float* b1   = (const float*)d_in[2];
    const float* g1   = (const float*)d_in[3];
    const float* be1  = (const float*)d_in[4];
    const float* w2   = (const float*)d_in[5];
    const float* b2   = (const float*)d_in[6];
    const float* g2   = (const float*)d_in[7];
    const float* be2  = (const float*)d_in[8];
    const float* core = (const float*)d_in[9];
    const float* clad = (const float*)d_in[10];
    const float* ferr = (const float*)d_in[11];
    const float* anom = (const float*)d_in[12];
    const float* qa1w = (const float*)d_in[13];
    const float* qa1b = (const float*)d_in[14];
    const float* qa2w = (const float*)d_in[15];
    const float* qa2b = (const float*)d_in[16];
    const float* clsw = (const float*)d_in[17];
    const float* clsb = (const float*)d_in[18];

    char* ws = (char*)d_ws;
    float* stats = (float*)ws;
    float* s1 = stats + 0;
    float* q1 = stats + 64;
    float* s2 = stats + 128;
    float* q2 = stats + 256;
    float* sc1 = stats + 384;
    float* sh1 = stats + 448;
    float* sc2 = stats + 512;
    float* sh2 = stats + 640;
    u16*   hraw = (u16*)(ws + 4096);                       // 33,554,432 B
    float* wcat = (float*)(ws + 33558528ull);              // 285,696 B
    u16*   w2bf = (u16*)(ws + 33844224ull);                // 147,456 B
    u16*   whi  = (u16*)(ws + 33991680ull);                // 142,848 B
    u16*   wlo  = (u16*)(ws + 34134528ull);                // 142,848 B
    float* dout = (float*)d_out;

    hipMemsetAsync(stats, 0, 384 * sizeof(float), stream);
    hipMemcpyAsync(wcat,             core, 10 * 1152 * 4, hipMemcpyDeviceToDevice, stream);
    hipMemcpyAsync(wcat + 10 * 1152, clad, 10 * 1152 * 4, hipMemcpyDeviceToDevice, stream);
    hipMemcpyAsync(wcat + 20 * 1152, ferr, 10 * 1152 * 4, hipMemcpyDeviceToDevice, stream);
    hipMemcpyAsync(wcat + 30 * 1152, anom, 32 * 1152 * 4, hipMemcpyDeviceToDevice, stream);

    dim3 blk(256);
    k_cvt<<<288, blk, 0, stream>>>(w2, w2bf, 73728);
    k_cvt_split<<<279, blk, 0, stream>>>(wcat, whi, wlo, 71424);

    k_conv1<<<dim3(256, 2, 4), blk, 0, stream>>>(x, w1, b1, hraw, s1, q1);
    k_finalize<<<1, 128, 0, stream>>>(s1, q1, g1, be1, sc1, sh1, 64);
    k_bnrelu_h<<<16384, blk, 0, stream>>>((ushort4*)hraw, sc1, sh1);

    k_conv2_mf<<<dim3(256, 4), blk, 0, stream>>>(hraw, w2bf, b2, dout + O0);
    k_stats<<<dim3(128, 8), blk, 0, stream>>>(dout + O0, s2, q2);
    k_finalize<<<1, 128, 0, stream>>>(s2, q2, g2, be2, sc2, sh2, 128);
    k_bnrelu<<<32768, blk, 0, stream>>>((float4*)(dout + O0), sc2, sh2, 128);

    k_match_mf<<<dim3(256, 4), blk, 0, stream>>>(dout + O0, whi, wlo, dout + O3, dout + O4);
    k_heads<<<dim3(256, 4), blk, 0, stream>>>(dout, qa1w, qa1b, qa2w, qa2b, clsw, clsb, dout);
}

// Round 5
// 1307.593 us; speedup vs baseline: 7.4384x; 1.2538x over previous
//
#include <hip/hip_runtime.h>
#include <hip/hip_bf16.h>

typedef unsigned short u16;
typedef __attribute__((ext_vector_type(8)))  short s8v;
typedef __attribute__((ext_vector_type(4)))  short s4v;
typedef __attribute__((ext_vector_type(16))) float f16v;

#define HWX 65536
#define EPSV 1e-5f

// d_out element offsets (fp32), concatenated tuple order
#define O0 0u
#define O1 33554432u
#define O2 34340864u
#define O3 34603008u
#define O4 42467328u
#define O5 50855936u
#define O6 51118080u
#define O7 51904512u

__device__ __forceinline__ float u2f(u16 u) {
    union { unsigned int i; float f; } v; v.i = ((unsigned int)u) << 16; return v.f;
}
__device__ __forceinline__ u16 f2u(float f) {
    __hip_bfloat16 h = __float2bfloat16(f);
    return *reinterpret_cast<u16*>(&h);
}
__device__ __forceinline__ s8v ld8(const u16* p) {
    union { s8v v; s4v h[2]; } r;
    r.h[0] = *(const s4v*)p;
    r.h[1] = *(const s4v*)(p + 4);
    return r.v;
}

#define PHYS(i) ((i) + ((i) >> 5))

// ---------------- conv1: 3->64 fp32 direct (swizzled LDS), bf16 out + stats --
__global__ __launch_bounds__(256) void k_conv1(const float* __restrict__ x,
                                               const float* __restrict__ w,
                                               const float* __restrict__ bias,
                                               u16* __restrict__ out,
                                               float* __restrict__ ssum,
                                               float* __restrict__ sqsum) {
    const int h = blockIdx.x, cb = blockIdx.y, b = blockIdx.z;
    const int t = threadIdx.x;
    const int pg = t & 31, cg = t >> 5;
    const int px0 = pg * 8, c0 = cg * 4;
    const int cbase = cb * 32;

    __shared__ float xs[3][3][266];
    __shared__ float wl[27 * 33];

    float acc[4][8];
    #pragma unroll
    for (int c = 0; c < 4; c++) {
        float bv = bias[cbase + c0 + c];
        #pragma unroll
        for (int p = 0; p < 8; p++) acc[c][p] = bv;
    }

    for (int idx = t; idx < 3 * 768; idx += 256) {
        int ci = idx / 768, rem = idx - ci * 768;
        int r = rem >> 8, px = rem & 255;
        int hh = h + r - 1;
        float v = 0.f;
        if ((unsigned)hh < 256u)
            v = x[((size_t)(b * 3 + ci) * 256 + hh) * 256 + px];
        xs[ci][r][PHYS(1 + px)] = v;
    }
    if (t < 18) {
        int ci = t / 6, rr = t - ci * 6;
        xs[ci][rr >> 1][(rr & 1) ? PHYS(257) : 0] = 0.f;
    }
    for (int idx = t; idx < 27 * 32; idx += 256) {
        int co = idx / 27, rem = idx - co * 27;
        wl[rem * 33 + co] = w[(cbase + co) * 27 + rem];
    }
    __syncthreads();

    for (int ci = 0; ci < 3; ci++) {
        #pragma unroll
        for (int kh = 0; kh < 3; kh++) {
            float xv[10];
            #pragma unroll
            for (int j = 0; j < 10; j++) xv[j] = xs[ci][kh][PHYS(px0 + j)];
            float wv[3][4];
            #pragma unroll
            for (int kw = 0; kw < 3; kw++)
                #pragma unroll
                for (int c = 0; c < 4; c++)
                    wv[kw][c] = wl[(ci * 9 + kh * 3 + kw) * 33 + c0 + c];
            #pragma unroll
            for (int c = 0; c < 4; c++)
                #pragma unroll
                for (int p = 0; p < 8; p++)
                    acc[c][p] += xv[p] * wv[0][c] + xv[p + 1] * wv[1][c]
                               + xv[p + 2] * wv[2][c];
        }
    }

    #pragma unroll
    for (int c = 0; c < 4; c++) {
        int cm = cbase + c0 + c;
        u16* op = out + (((size_t)(b * 64 + cm) * 256 + h) * 256 + px0);
        #pragma unroll
        for (int p = 0; p < 8; p++) op[p] = f2u(acc[c][p]);
    }

    __syncthreads();
    float* red = &xs[0][0][0];
    #pragma unroll
    for (int c = 0; c < 4; c++) {
        float sv = 0.f, qv = 0.f;
        #pragma unroll
        for (int p = 0; p < 8; p++) { sv += acc[c][p]; qv += acc[c][p] * acc[c][p]; }
        red[(c0 + c) * 33 + pg] = sv;
        red[1056 + (c0 + c) * 33 + pg] = qv;
    }
    __syncthreads();
    if (t < 64) {
        int co = t & 31, v = t >> 5;
        const float* base = red + v * 1056 + co * 33;
        float sum = 0.f;
        #pragma unroll
        for (int i = 0; i < 32; i++) sum += base[i];
        atomicAdd((v ? sqsum : ssum) + cbase + co, sum);
    }
}

// ---------------- finalize BN ----------------
__global__ void k_finalize(const float* __restrict__ s, const float* __restrict__ q,
                           const float* __restrict__ g, const float* __restrict__ be,
                           float* __restrict__ sc, float* __restrict__ sh, int C) {
    int c = threadIdx.x;
    if (c >= C) return;
    const float invN = 1.f / 262144.f;
    float m = s[c] * invN;
    float v = fmaxf(q[c] * invN - m * m, 0.f);
    float scale = g[c] * rsqrtf(v + EPSV);
    sc[c] = scale;
    sh[c] = be[c] - m * scale;
}

// ---------------- BN+ReLU on bf16 buffer (in place) ----------------
__global__ __launch_bounds__(256) void k_bnrelu_h(ushort4* __restrict__ buf,
                                                  const float* __restrict__ sc,
                                                  const float* __restrict__ sh) {
    size_t i = (size_t)blockIdx.x * 256 + threadIdx.x;
    int c = (int)(i >> 14) & 63;
    float s = sc[c], h0 = sh[c];
    ushort4 r = buf[i];
    ushort4 o;
    o.x = f2u(fmaxf(u2f(r.x) * s + h0, 0.f));
    o.y = f2u(fmaxf(u2f(r.y) * s + h0, 0.f));
    o.z = f2u(fmaxf(u2f(r.z) * s + h0, 0.f));
    o.w = f2u(fmaxf(u2f(r.w) * s + h0, 0.f));
    buf[i] = o;
}

// ---------------- BN+ReLU fp32 (features, in place) ----------------
__global__ __launch_bounds__(256) void k_bnrelu(float4* __restrict__ buf,
                                                const float* __restrict__ sc,
                                                const float* __restrict__ sh, int C) {
    size_t i = (size_t)blockIdx.x * 256 + threadIdx.x;
    int c = (int)(i >> 14) % C;
    float s = sc[c], h0 = sh[c];
    float4 r = buf[i];
    float4 o;
    o.x = fmaxf(r.x * s + h0, 0.f);
    o.y = fmaxf(r.y * s + h0, 0.f);
    o.z = fmaxf(r.z * s + h0, 0.f);
    o.w = fmaxf(r.w * s + h0, 0.f);
    buf[i] = o;
}

// ---------------- per-channel stats over raw conv2 out ----------------
__global__ __launch_bounds__(256) void k_stats(const float* __restrict__ raw,
                                               float* __restrict__ ssum,
                                               float* __restrict__ sqsum) {
    const int co = blockIdx.x, seg = blockIdx.y;
    const int t = threadIdx.x;
    __shared__ float red[8];
    float s = 0.f, q = 0.f;
    for (int b = 0; b < 4; b++) {
        const float4* p = (const float4*)(raw + ((size_t)(b * 128 + co) * HWX) + seg * 8192);
        for (int i = t; i < 2048; i += 256) {
            float4 v = p[i];
            s += v.x + v.y + v.z + v.w;
            q += v.x * v.x + v.y * v.y + v.z * v.z + v.w * v.w;
        }
    }
    #pragma unroll
    for (int off = 32; off; off >>= 1) {
        s += __shfl_down(s, off, 64);
        q += __shfl_down(q, off, 64);
    }
    int lane = t & 63, wv = t >> 6;
    if (lane == 0) { red[wv] = s; red[4 + wv] = q; }
    __syncthreads();
    if (t == 0) atomicAdd(&ssum[co], red[0] + red[1] + red[2] + red[3]);
    else if (t == 1) atomicAdd(&sqsum[co], red[4] + red[5] + red[6] + red[7]);
}

// ---------------- weight pre-tiling ----------------
// match: wtile[(ch*2+plane)*9984 + (kw*64+co)*52 + kh*16+cil], ch=ci/16, 8 chunks
__global__ void k_prep_w(const float* __restrict__ wcat, u16* __restrict__ wtile) {
    int i = blockIdx.x * 256 + threadIdx.x;
    if (i >= 159744) return;
    int ch = i / 19968, rem = i - ch * 19968;
    int pl = rem / 9984; rem -= pl * 9984;
    int kwco = rem / 52, k = rem - kwco * 52;
    int kw = kwco >> 6, co = kwco & 63;
    u16 v = 0;
    if (k < 48 && co < 62) {
        int kh = k >> 4, ci = ch * 16 + (k & 15);
        float f = wcat[(size_t)co * 1152 + ci * 9 + kh * 3 + kw];
        u16 hv = f2u(f);
        v = pl ? f2u(f - u2f(hv)) : hv;
    }
    wtile[i] = v;
}
// conv2: wtile2[ch*9984... no: (kw*128+co)*52+k per chunk of 16 ci, 4 chunks
__global__ void k_prep_w2(const float* __restrict__ w2, u16* __restrict__ wtile2) {
    int i = blockIdx.x * 256 + threadIdx.x;
    if (i >= 79872) return;                 // 4 * 3*128*52
    int ch = i / 19968, rem = i - ch * 19968;
    int kwco = rem / 52, k = rem - kwco * 52;
    int kw = kwco >> 7, co = kwco & 127;
    u16 v = 0;
    if (k < 48) {
        int kh = k >> 4, ci = ch * 16 + (k & 15);
        v = f2u(w2[((size_t)co * 64 + ci) * 9 + kh * 3 + kw]);
    }
    wtile2[i] = v;
}

// ---------------- conv2 MFMA: 64->128, bf16 in, fp32 raw out ----------------
__global__ __launch_bounds__(256, 2) void k_conv2_mf(
    const u16* __restrict__ hb, const u16* __restrict__ wtile2,
    const float* __restrict__ bias, float* __restrict__ out)
{
    const int h = blockIdx.x, b = blockIdx.y;
    const int t = threadIdx.x, l = t & 63, wv = t >> 6;
    const int kg = (l >> 5) * 8, nn = l & 31;

    __shared__ u16 xs[258 * 52];
    __shared__ u16 wl[3 * 128 * 52];

    f16v acc[2][4];
    #pragma unroll
    for (int pt = 0; pt < 2; pt++)
        #pragma unroll
        for (int s = 0; s < 4; s++)
            #pragma unroll
            for (int r = 0; r < 16; r++) acc[pt][s][r] = 0.f;

    for (int ch = 0; ch < 4; ch++) {
        for (int i = t; i < 19968; i += 256) wl[i] = wtile2[ch * 19968 + i];
        #pragma unroll
        for (int ci = 0; ci < 16; ci++) {
            const u16* srcc = hb + ((size_t)(b * 64 + ch * 16 + ci) << 16);
            #pragma unroll
            for (int r = 0; r < 3; r++) {
                int hh = h + r - 1;
                bool vr = (unsigned)hh < 256u;
                const u16* src = srcc + ((size_t)hh << 8);
                u16 v = (vr && t >= 1) ? src[t - 1] : (u16)0;
                xs[t * 52 + r * 16 + ci] = v;
                if (t < 2) {
                    u16 v2 = (vr && t == 0) ? src[255] : (u16)0;
                    xs[(256 + t) * 52 + r * 16 + ci] = v2;
                }
            }
        }
        __syncthreads();
        #pragma unroll
        for (int kw = 0; kw < 3; kw++) {
            #pragma unroll
            for (int ks = 0; ks < 3; ks++) {
                int k0 = ks * 16 + kg;
                s8v af[4], bf[2];
                #pragma unroll
                for (int s = 0; s < 4; s++)
                    af[s] = ld8(&wl[(kw * 128 + s * 32 + nn) * 52 + k0]);
                #pragma unroll
                for (int pt = 0; pt < 2; pt++)
                    bf[pt] = ld8(&xs[((wv * 2 + pt) * 32 + nn + kw) * 52 + k0]);
                #pragma unroll
                for (int pt = 0; pt < 2; pt++)
                    #pragma unroll
                    for (int s = 0; s < 4; s++)
                        acc[pt][s] = __builtin_amdgcn_mfma_f32_32x32x16_bf16(
                            af[s], bf[pt], acc[pt][s], 0, 0, 0);
            }
        }
        __syncthreads();
    }

    #pragma unroll
    for (int pt = 0; pt < 2; pt++) {
        int px = (wv * 2 + pt) * 32 + nn;
        #pragma unroll
        for (int s = 0; s < 4; s++) {
            #pragma unroll
            for (int r = 0; r < 16; r++) {
                int co = s * 32 + (r & 3) + 8 * (r >> 2) + 4 * (l >> 5);
                out[(((size_t)b * 128 + co) * 256 + h) * 256 + px] = acc[pt][s][r] + bias[co];
            }
        }
    }
}

// ---------------- match MFMA: 128->62, 3-term split, two-pass LDS ----------
__global__ __launch_bounds__(256, 2) void k_match_mf(
    const float* __restrict__ feat, const u16* __restrict__ wtile,
    float* __restrict__ out_all, float* __restrict__ out_anom)
{
    const int h = blockIdx.x, b = blockIdx.y;
    const int t = threadIdx.x, l = t & 63, wv = t >> 6;
    const int kg = (l >> 5) * 8, nn = l & 31;

    __shared__ u16 xs[258 * 52];     // one plane at a time (hi then lo)
    __shared__ u16 wl[2][9984];      // hi, lo weights for current chunk

    f16v acc[2][2];
    #pragma unroll
    for (int pt = 0; pt < 2; pt++)
        #pragma unroll
        for (int s = 0; s < 2; s++)
            #pragma unroll
            for (int r = 0; r < 16; r++) acc[pt][s][r] = 0.f;

    for (int ch = 0; ch < 8; ch++) {
        for (int i = t; i < 9984; i += 256) wl[0][i] = wtile[(ch * 2 + 0) * 9984 + i];
        for (int i = t; i < 9984; i += 256) wl[1][i] = wtile[(ch * 2 + 1) * 9984 + i];
        #pragma unroll
        for (int pass = 0; pass < 2; pass++) {
            // stage x plane (hi: pass 0, lo: pass 1), division-free
            #pragma unroll
            for (int ci = 0; ci < 16; ci++) {
                const float* srcc = feat + ((size_t)(b * 128 + ch * 16 + ci) << 16);
                #pragma unroll
                for (int r = 0; r < 3; r++) {
                    int hh = h + r - 1;
                    bool vr = (unsigned)hh < 256u;
                    const float* src = srcc + ((size_t)hh << 8);
                    float v = (vr && t >= 1) ? src[t - 1] : 0.f;
                    u16 hv = f2u(v);
                    xs[t * 52 + r * 16 + ci] = pass ? f2u(v - u2f(hv)) : hv;
                    if (t < 2) {
                        float v2 = (vr && t == 0) ? src[255] : 0.f;
                        u16 hv2 = f2u(v2);
                        xs[(256 + t) * 52 + r * 16 + ci] = pass ? f2u(v2 - u2f(hv2)) : hv2;
                    }
                }
            }
            __syncthreads();
            #pragma unroll
            for (int kw = 0; kw < 3; kw++) {
                #pragma unroll
                for (int ks = 0; ks < 3; ks++) {
                    int k0 = ks * 16 + kg;
                    s8v xfr[2];
                    #pragma unroll
                    for (int pt = 0; pt < 2; pt++)
                        xfr[pt] = ld8(&xs[((wv * 2 + pt) * 32 + nn + kw) * 52 + k0]);
                    s8v ah0 = ld8(&wl[0][(kw * 64 + nn) * 52 + k0]);
                    s8v ah1 = ld8(&wl[0][(kw * 64 + 32 + nn) * 52 + k0]);
                    if (pass == 0) {
                        s8v al0 = ld8(&wl[1][(kw * 64 + nn) * 52 + k0]);
                        s8v al1 = ld8(&wl[1][(kw * 64 + 32 + nn) * 52 + k0]);
                        #pragma unroll
                        for (int pt = 0; pt < 2; pt++) {
                            acc[pt][0] = __builtin_amdgcn_mfma_f32_32x32x16_bf16(ah0, xfr[pt], acc[pt][0], 0, 0, 0);
                            acc[pt][0] = __builtin_amdgcn_mfma_f32_32x32x16_bf16(al0, xfr[pt], acc[pt][0], 0, 0, 0);
                            acc[pt][1] = __builtin_amdgcn_mfma_f32_32x32x16_bf16(ah1, xfr[pt], acc[pt][1], 0, 0, 0);
                            acc[pt][1] = __builtin_amdgcn_mfma_f32_32x32x16_bf16(al1, xfr[pt], acc[pt][1], 0, 0, 0);
                        }
                    } else {
                        #pragma unroll
                        for (int pt = 0; pt < 2; pt++) {
                            acc[pt][0] = __builtin_amdgcn_mfma_f32_32x32x16_bf16(ah0, xfr[pt], acc[pt][0], 0, 0, 0);
                            acc[pt][1] = __builtin_amdgcn_mfma_f32_32x32x16_bf16(ah1, xfr[pt], acc[pt][1], 0, 0, 0);
                        }
                    }
                }
            }
            __syncthreads();
        }
    }

    #pragma unroll
    for (int pt = 0; pt < 2; pt++) {
        int px = (wv * 2 + pt) * 32 + nn;
        #pragma unroll
        for (int s = 0; s < 2; s++) {
            #pragma unroll
            for (int r = 0; r < 16; r++) {
                int cm = s * 32 + (r & 3) + 8 * (r >> 2) + 4 * (l >> 5);
                float sg = 1.f / (1.f + __expf(-acc[pt][s][r]));
                if (cm < 30)
                    out_all[(((size_t)b * 30 + cm) * 256 + h) * 256 + px] = sg;
                else if (cm < 62)
                    out_anom[(((size_t)b * 32 + cm - 30) * 256 + h) * 256 + px] = sg;
            }
        }
    }
}

// ---------------- fused 1x1 heads ----------------
__global__ __launch_bounds__(256) void k_heads(const float* __restrict__ dout,
                                               const float* __restrict__ qa1w,
                                               const float* __restrict__ qa1b,
                                               const float* __restrict__ qa2w,
                                               const float* __restrict__ qa2b,
                                               const float* __restrict__ clsw,
                                               const float* __restrict__ clsb,
                                               float* __restrict__ out) {
    __shared__ __align__(16) float lw[190 * 68];
    __shared__ float lq2[64];
    __shared__ float lb[70];
    const int t = threadIdx.x;
    for (int i = t; i < 190 * 64; i += 256) { int j = i / 190, k = i - j * 190; lw[k * 68 + j] = qa1w[i]; }
    for (int i = t; i < 190 * 4;  i += 256) { int c = i / 190, k = i - c * 190; lw[k * 68 + 64 + c] = clsw[i]; }
    if (t < 64) { lq2[t] = qa2w[t]; lb[t] = qa1b[t]; }
    if (t < 4) lb[64 + t] = clsb[t];
    if (t == 0) lb[68] = qa2b[0];
    __syncthreads();
    const int px = blockIdx.x * 256 + t;
    const int b = blockIdx.y;
    const float* feat = dout + O0 + (size_t)b * 128 * HWX + px;
    const float* amat = dout + O3 + (size_t)b * 30 * HWX + px;
    const float* anm  = dout + O4 + (size_t)b * 32 * HWX + px;
    float acc[64];
    #pragma unroll
    for (int j = 0; j < 64; j++) acc[j] = lb[j];
    float c0 = lb[64], c1 = lb[65], c2 = lb[66], c3 = lb[67];
    for (int k = 0; k < 190; k++) {
        float val;
        if (k < 128)      val = feat[(size_t)k * HWX];
        else if (k < 158) val = amat[(size_t)(k - 128) * HWX];
        else              val = anm[(size_t)(k - 158) * HWX];
        const float4* wr = (const float4*)(lw + k * 68);
        #pragma unroll
        for (int j = 0; j < 16; j++) {
            float4 wvv = wr[j];
            acc[4 * j + 0] += val * wvv.x;
            acc[4 * j + 1] += val * wvv.y;
            acc[4 * j + 2] += val * wvv.z;
            acc[4 * j + 3] += val * wvv.w;
        }
        float4 wc = wr[16];
        c0 += val * wc.x; c1 += val * wc.y; c2 += val * wc.z; c3 += val * wc.w;
    }
    float qa = lb[68];
    #pragma unroll
    for (int j = 0; j < 64; j++) qa += fmaxf(acc[j], 0.f) * lq2[j];
    float quality = 1.f / (1.f + __expf(-qa));
    float m = fmaxf(c0, fmaxf(c1, c2));
    float e0 = __expf(c0 - m), e1 = __expf(c1 - m), e2 = __expf(c2 - m);
    float inv = 1.f / (e0 + e1 + e2);
    size_t hw = (size_t)px;
    out[O1 + ((size_t)b * 3 + 0) * HWX + hw] = c0;
    out[O1 + ((size_t)b * 3 + 1) * HWX + hw] = c1;
    out[O1 + ((size_t)b * 3 + 2) * HWX + hw] = c2;
    out[O2 + (size_t)b * HWX + hw] = c3;
    out[O5 + (size_t)b * HWX + hw] = quality;
    out[O6 + ((size_t)b * 3 + 0) * HWX + hw] = e0 * inv;
    out[O6 + ((size_t)b * 3 + 1) * HWX + hw] = e1 * inv;
    out[O6 + ((size_t)b * 3 + 2) * HWX + hw] = e2 * inv;
    out[O7 + (size_t)b * HWX + hw] = 1.f / (1.f + __expf(-c3));
}

extern "C" void kernel_launch(void* const* d_in, const int* in_sizes, int n_in,
                              void* d_out, int out_size, void* d_ws, size_t ws_size,
                              hipStream_t stream) {
    (void)in_sizes; (void)n_in; (void)out_size; (void)ws_size;
    const float* x    = (const float*)d_in[0];
    const float* w1   = (const float*)d_in[1];
    const float* b1   = (const float*)d_in[2];
    const float* g1   = (const float*)d_in[3];
    const float* be1  = (const float*)d_in[4];
    const float* w2   = (const float*)d_in[5];
    const float* b2   = (const float*)d_in[6];
    const float* g2   = (const float*)d_in[7];
    const float* be2  = (const float*)d_in[8];
    const float* core = (const float*)d_in[9];
    const float* clad = (const float*)d_in[10];
    const float* ferr = (const float*)d_in[11];
    const float* anom = (const float*)d_in[12];
    const float* qa1w = (const float*)d_in[13];
    const float* qa1b = (const float*)d_in[14];
    const float* qa2w = (const float*)d_in[15];
    const float* qa2b = (const float*)d_in[16];
    const float* clsw = (const float*)d_in[17];
    const float* clsb = (const float*)d_in[18];

    char* ws = (char*)d_ws;
    float* stats = (float*)ws;
    float* s1 = stats + 0;
    float* q1 = stats + 64;
    float* s2 = stats + 128;
    float* q2 = stats + 256;
    float* sc1 = stats + 384;
    float* sh1 = stats + 448;
    float* sc2 = stats + 512;
    float* sh2 = stats + 640;
    u16*   hraw   = (u16*)(ws + 4096);                // 33,554,432 B
    float* wcat   = (float*)(ws + 33558528ull);       // 285,696 B
    u16*   wtile2 = (u16*)(ws + 33844224ull);         // 79,872*2 B
    u16*   wtile  = (u16*)(ws + 34004224ull);         // 159,744*2 B
    float* dout = (float*)d_out;

    hipMemsetAsync(stats, 0, 384 * sizeof(float), stream);
    hipMemcpyAsync(wcat,             core, 10 * 1152 * 4, hipMemcpyDeviceToDevice, stream);
    hipMemcpyAsync(wcat + 10 * 1152, clad, 10 * 1152 * 4, hipMemcpyDeviceToDevice, stream);
    hipMemcpyAsync(wcat + 20 * 1152, ferr, 10 * 1152 * 4, hipMemcpyDeviceToDevice, stream);
    hipMemcpyAsync(wcat + 30 * 1152, anom, 32 * 1152 * 4, hipMemcpyDeviceToDevice, stream);

    dim3 blk(256);
    k_prep_w2<<<312, blk, 0, stream>>>(w2, wtile2);
    k_prep_w<<<624, blk, 0, stream>>>(wcat, wtile);

    k_conv1<<<dim3(256, 2, 4), blk, 0, stream>>>(x, w1, b1, hraw, s1, q1);
    k_finalize<<<1, 128, 0, stream>>>(s1, q1, g1, be1, sc1, sh1, 64);
    k_bnrelu_h<<<16384, blk, 0, stream>>>((ushort4*)hraw, sc1, sh1);

    k_conv2_mf<<<dim3(256, 4), blk, 0, stream>>>(hraw, wtile2, b2, dout + O0);
    k_stats<<<dim3(128, 8), blk, 0, stream>>>(dout + O0, s2, q2);
    k_finalize<<<1, 128, 0, stream>>>(s2, q2, g2, be2, sc2, sh2, 128);
    k_bnrelu<<<32768, blk, 0, stream>>>((float4*)(dout + O0), sc2, sh2, 128);

    k_match_mf<<<dim3(256, 4), blk, 0, stream>>>(dout + O0, wtile, dout + O3, dout + O4);
    k_heads<<<dim3(256, 4), blk, 0, stream>>>(dout, qa1w, qa1b, qa2w, qa2b, clsw, clsb, dout);
}